// Round 7
// baseline (169.118 us; speedup 1.0000x reference)
//
#include <hip/hip_runtime.h>
#include <hip/hip_bf16.h>
#include <math.h>

#define BTOT 16384

typedef __attribute__((ext_vector_type(8))) short short8;
typedef __attribute__((ext_vector_type(4))) float f32x4;
typedef __attribute__((ext_vector_type(16))) float f32x16;

__device__ __forceinline__ float selu_f(float x) {
  const float scale = 1.0507009873554805f;
  const float alpha = 1.6732632423543772f;
  return scale * (x > 0.0f ? x : alpha * expm1f(x));
}

// ---------------- prep: p -> bf16 ----------------
__global__ __launch_bounds__(256) void convert_p_kernel(
    const float* __restrict__ p, __hip_bfloat16* __restrict__ out) {
  int i = (blockIdx.x * 256 + threadIdx.x) * 4;
  float4 v = *reinterpret_cast<const float4*>(p + i);
  out[i + 0] = __float2bfloat16(v.x);
  out[i + 1] = __float2bfloat16(v.y);
  out[i + 2] = __float2bfloat16(v.z);
  out[i + 3] = __float2bfloat16(v.w);
}

// ---------------- prep: W[K][N] f32 -> Wt[N][K] bf16 (t-row excluded) ---------
__global__ __launch_bounds__(256) void transpose_w_kernel(
    const float* __restrict__ W, __hip_bfloat16* __restrict__ Wt, int K, int N) {
  __shared__ float tile[32][33];
  const int kb = blockIdx.x * 32, nb = blockIdx.y * 32;
  const int tx = threadIdx.x & 31, ty = threadIdx.x >> 5;
  #pragma unroll
  for (int rr = 0; rr < 4; ++rr) {
    int kl = ty + rr * 8;
    tile[kl][tx] = W[(size_t)(kb + kl) * N + nb + tx];
  }
  __syncthreads();
  #pragma unroll
  for (int rr = 0; rr < 4; ++rr) {
    int nl = ty + rr * 8;
    Wt[(size_t)(nb + nl) * K + kb + tx] = __float2bfloat16(tile[tx][nl]);
  }
}

// ---------------- MFMA MLP layer ----------------
// MODE 0: selu + bf16 store (hidden).  MODE 1: clip(+-20) + bf16 store (final).
// BK=32 everywhere: 32KB LDS/block -> 4-5 blocks/CU (m97 structure).
template<int BK, int MODE>
__global__ __launch_bounds__(256) void mlp_mfma_kernel(
    const __hip_bfloat16* __restrict__ X, int ldx, int Kc,
    const float* __restrict__ tvec,
    const __hip_bfloat16* __restrict__ Wt,    // [N][Kc] bf16
    const float* __restrict__ Wlast,          // t-row, fp32 [N]
    const float* __restrict__ bias,           // fp32 [N]
    __hip_bfloat16* __restrict__ Yout, int ldy) {
  constexpr int NBLK = BK / 8;
  constexpr int AB = 128 * BK * 2;
  constexpr int IPW = AB / 1024 / 4;
  __shared__ char lds[4 * AB];
  const int tid = threadIdx.x;
  const int w = tid >> 6, lane = tid & 63;
  const int wr = w >> 1, wc = w & 1;
  const int rowbase = blockIdx.x * 128, colbase = blockIdx.y * 128;

  const __hip_bfloat16* srcA[IPW];
  const __hip_bfloat16* srcB[IPW];
  int ldsoff[IPW];
  #pragma unroll
  for (int i = 0; i < IPW; ++i) {
    int f = (w * IPW + i) * 64 + lane;
    int r = f / NBLK, slot = f % NBLK;
    int kb = slot ^ (r & (NBLK - 1));
    srcA[i] = X + (size_t)(rowbase + r) * ldx + kb * 8;
    srcB[i] = Wt + (size_t)(colbase + r) * Kc + kb * 8;
    ldsoff[i] = (w * IPW + i) * 1024;
  }

  f32x4 acc[4][4] = {};

  int aoff[4], amask[4], boff[4], bmask[4];
  #pragma unroll
  for (int i = 0; i < 4; ++i) {
    int ra = wr * 64 + i * 16 + (lane & 15);
    aoff[i] = ra * BK * 2;
    amask[i] = ra & (NBLK - 1);
    int cb = wc * 64 + i * 16 + (lane & 15);
    boff[i] = cb * BK * 2;
    bmask[i] = cb & (NBLK - 1);
  }
  const int kgrp = lane >> 4;

  auto stage_tile = [&](int buf, int t) {
    char* ab = lds + buf * 2 * AB;
    #pragma unroll
    for (int i = 0; i < IPW; ++i) {
      __builtin_amdgcn_global_load_lds(
          (const __attribute__((address_space(1))) void*)(srcA[i] + t * BK),
          (__attribute__((address_space(3))) void*)(ab + ldsoff[i]), 16, 0, 0);
      __builtin_amdgcn_global_load_lds(
          (const __attribute__((address_space(1))) void*)(srcB[i] + t * BK),
          (__attribute__((address_space(3))) void*)(ab + AB + ldsoff[i]), 16, 0, 0);
    }
  };

  auto compute_tile = [&](int buf) {
    const char* Abse = lds + buf * 2 * AB;
    const char* Bbse = Abse + AB;
    #pragma unroll
    for (int kh = 0; kh < BK / 32; ++kh) {
      short8 a[4], b[4];
      const int kb = kh * 4 + kgrp;
      #pragma unroll
      for (int i = 0; i < 4; ++i) {
        a[i] = *reinterpret_cast<const short8*>(Abse + aoff[i] + ((kb ^ amask[i]) * 16));
        b[i] = *reinterpret_cast<const short8*>(Bbse + boff[i] + ((kb ^ bmask[i]) * 16));
      }
      #pragma unroll
      for (int i = 0; i < 4; ++i)
        #pragma unroll
        for (int j = 0; j < 4; ++j)
          acc[i][j] = __builtin_amdgcn_mfma_f32_16x16x32_bf16(a[i], b[j], acc[i][j], 0, 0, 0);
    }
  };

  const int nt = Kc / BK;
  stage_tile(0, 0);
  asm volatile("s_waitcnt vmcnt(0)" ::: "memory");
  __syncthreads();
  int buf = 0;
  #pragma unroll 1
  for (int t = 0; t < nt - 1; ++t) {
    stage_tile(buf ^ 1, t + 1);
    compute_tile(buf);
    asm volatile("s_waitcnt vmcnt(0)" ::: "memory");
    __syncthreads();
    buf ^= 1;
  }
  compute_tile(buf);

  const int colloc = lane & 15;
  const int rowgrp = lane >> 4;
  float wl[4], bb[4];
  #pragma unroll
  for (int j = 0; j < 4; ++j) {
    int col = colbase + wc * 64 + j * 16 + colloc;
    wl[j] = Wlast[col];
    bb[j] = bias[col];
  }
  #pragma unroll
  for (int i = 0; i < 4; ++i) {
    #pragma unroll
    for (int e = 0; e < 4; ++e) {
      int row = rowbase + wr * 64 + i * 16 + rowgrp * 4 + e;
      float tv = tvec[row];
      #pragma unroll
      for (int j = 0; j < 4; ++j) {
        float v = acc[i][j][e] + tv * wl[j] + bb[j];
        if (MODE == 0) v = selu_f(v);
        else           v = fminf(fmaxf(v, -20.f), 20.f);
        int col = colbase + wc * 64 + j * 16 + colloc;
        Yout[(size_t)row * ldy + col] = __float2bfloat16(v);
      }
    }
  }
}

// ---------------- expm: LDS-free in-register power chain ----------------
// One 32x32 matrix per wave. E = sum_{k=0..8} (u^k/k!) A^k, u = dt*2^-s, A raw
// bf16. A-operand frags of A loaded DIRECTLY from global (row-major bf16 memory
// == operand format). Chain P(k+1) = A * P(k): D-layout -> B-operand conversion
// is pure in-register (16x shfl_xor(32) + bf16 pack), 2 MFMA per product, zero
// LDS in the chain. One initial LDS transpose gives D-layout f32 A.
// Same (lane,e)->k bijection for A and B as round-5/6 (HW-verified).
// E^(2^s) q via 2^s exact f32 mat-vecs (butterfly reduce).
#define WAITLDS asm volatile("s_waitcnt lgkmcnt(0)" ::: "memory")

__device__ __forceinline__ unsigned int bf16r(float x) {
  return (__float_as_uint(x) + 0x8000u) >> 16;
}

// D-layout f32 X -> B-operand frags (col C, k = 16h + 8G + e)
__device__ __forceinline__ void d2b(const float (&X)[16], int G, short8 (&bfr)[2]) {
  float oth[16];
  #pragma unroll
  for (int i = 0; i < 16; ++i) oth[i] = __shfl_xor(X[i], 32);
  #pragma unroll
  for (int h = 0; h < 2; ++h) {
    float r8[8];
    #pragma unroll
    for (int j2 = 0; j2 < 8; ++j2) {
      // rows 16h+8G+j2: G=0: j2<4 -> own[8h+j2], else oth[8h+j2-4]
      //                 G=1: j2<4 -> oth[8h+4+j2], else own[8h+j2]
      float g0 = (j2 < 4) ? X[8 * h + j2] : oth[8 * h + j2 - 4];
      float g1 = (j2 < 4) ? oth[8 * h + 4 + j2] : X[8 * h + j2];
      r8[j2] = G ? g1 : g0;
    }
    union { short8 s8; unsigned int u[4]; } bu;
    #pragma unroll
    for (int j = 0; j < 4; ++j)
      bu.u[j] = bf16r(r8[2 * j]) | (bf16r(r8[2 * j + 1]) << 16);
    bfr[h] = bu.s8;
  }
}

__global__ __launch_bounds__(256) void expm_chain_kernel(
    const __hip_bfloat16* __restrict__ flat,  // [B,1024] bf16, pre-clipped
    const float* __restrict__ q,
    const float* __restrict__ dtp,
    float* __restrict__ out_q,
    float* __restrict__ out_dlogp) {
  __shared__ __align__(16) unsigned int SL[4][16][33];   // pair slab, 8.4 KiB
  const int tid = threadIdx.x;
  const int w = tid >> 6, lane = tid & 63;
  const int C = lane & 31, G = lane >> 5;
  const int m = blockIdx.x * 4 + w;
  const float dt = dtp[0];

  // coalesced raw load: lane covers rows (l>>2), 16+(l>>2), col-pairs (l&3)*4..+4
  const uint4* fm = reinterpret_cast<const uint4*>(flat + (size_t)m * 1024);
  uint4 v0 = fm[lane];
  uint4 v1 = fm[lane + 64];

  // inf-norm (max row abs-sum) from raw loads
  float sa = 0.f, sb = 0.f;
  {
    unsigned int a0[4] = {v0.x, v0.y, v0.z, v0.w};
    unsigned int a1[4] = {v1.x, v1.y, v1.z, v1.w};
    #pragma unroll
    for (int i = 0; i < 4; ++i) {
      sa += fabsf(__uint_as_float(a0[i] << 16)) + fabsf(__uint_as_float(a0[i] & 0xFFFF0000u));
      sb += fabsf(__uint_as_float(a1[i] << 16)) + fabsf(__uint_as_float(a1[i] & 0xFFFF0000u));
    }
  }
  sa += __shfl_xor(sa, 1); sa += __shfl_xor(sa, 2);
  sb += __shfl_xor(sb, 1); sb += __shfl_xor(sb, 2);
  float nrm = fmaxf(sa, sb);
  #pragma unroll
  for (int off = 4; off < 64; off <<= 1) nrm = fmaxf(nrm, __shfl_xor(nrm, off));

  int s = 0;
  float anrm = dt * nrm;
  if (anrm > 1.5f) {
    s = (int)ceilf(log2f(anrm * (1.0f / 1.5f)));
    s = s < 1 ? 1 : (s > 6 ? 6 : s);
  }
  const float u = dt * exp2f(-(float)s);

  // A-operand frags of A, directly from global: row C, k=16h+8G+e
  short8 afr[2];
  {
    const char* base = reinterpret_cast<const char*>(flat) + (size_t)m * 2048 + C * 64 + G * 16;
    union { short8 s8; uint4 u4; } t0, t1;
    t0.u4 = *reinterpret_cast<const uint4*>(base);
    t1.u4 = *reinterpret_cast<const uint4*>(base + 32);
    afr[0] = t0.s8;
    afr[1] = t1.s8;
  }

  // initial LDS transpose -> D-layout f32 A
  {
    const int r0 = lane >> 2, kpb = (lane & 3) * 4;
    SL[w][kpb + 0][r0] = v0.x; SL[w][kpb + 1][r0] = v0.y;
    SL[w][kpb + 2][r0] = v0.z; SL[w][kpb + 3][r0] = v0.w;
    SL[w][kpb + 0][r0 + 16] = v1.x; SL[w][kpb + 1][r0 + 16] = v1.y;
    SL[w][kpb + 2][r0 + 16] = v1.z; SL[w][kpb + 3][r0 + 16] = v1.w;
  }
  WAITLDS;

  float A[16], dI[16];
  #pragma unroll
  for (int reg = 0; reg < 16; ++reg) {
    int rd = (reg & 3) + 8 * (reg >> 2) + 4 * G;
    unsigned int ww = SL[w][C >> 1][rd];
    unsigned int h16 = (C & 1) ? (ww >> 16) : (ww & 0xFFFFu);
    A[reg] = __uint_as_float(h16 << 16);
    dI[reg] = (rd == C) ? 1.0f : 0.0f;
  }

  // dlogp = dt * trace(raw A)
  {
    float tr = 0.f;
    #pragma unroll
    for (int reg = 0; reg < 16; ++reg) tr += dI[reg] * A[reg];
    #pragma unroll
    for (int off = 1; off < 64; off <<= 1) tr += __shfl_xor(tr, off);
    if (lane == 0) out_dlogp[m] = dt * tr;
  }

  // E = I + uA + sum_{k=2..8} (u^k/k!) A^k ; chain entirely in registers
  float E[16], P[16];
  #pragma unroll
  for (int i = 0; i < 16; ++i) { E[i] = dI[i] + u * A[i]; P[i] = A[i]; }

  float ck = u;
  #pragma unroll
  for (int k = 2; k <= 8; ++k) {
    short8 bfr[2];
    d2b(P, G, bfr);
    f32x16 acc = {};
    acc = __builtin_amdgcn_mfma_f32_32x32x16_bf16(afr[0], bfr[0], acc, 0, 0, 0);
    acc = __builtin_amdgcn_mfma_f32_32x32x16_bf16(afr[1], bfr[1], acc, 0, 0, 0);
    ck *= u * (1.0f / (float)k);
    #pragma unroll
    for (int i = 0; i < 16; ++i) { P[i] = acc[i]; E[i] += ck * P[i]; }
  }

  // E^(2^s) q via repeated exact f32 mat-vecs
  float qv = q[(size_t)m * 32 + C];
  const int nv = 1 << s;
  #pragma unroll 1
  for (int it = 0; it < nv; ++it) {
    float pr[16];
    #pragma unroll
    for (int i = 0; i < 16; ++i) pr[i] = E[i] * qv;
    #pragma unroll
    for (int off = 1; off < 32; off <<= 1) {
      #pragma unroll
      for (int i = 0; i < 16; ++i) pr[i] += __shfl_xor(pr[i], off);
    }
    float sel = 0.f;
    #pragma unroll
    for (int i = 0; i < 16; ++i)
      sel += (dI[i] != 0.0f) ? pr[i] : 0.f;
    qv = sel + __shfl_xor(sel, 32);
  }
  if (G == 0) out_q[(size_t)m * 32 + C] = qv;
}

extern "C" void kernel_launch(void* const* d_in, const int* in_sizes, int n_in,
                              void* d_out, int out_size, void* d_ws, size_t ws_size,
                              hipStream_t stream) {
  const float* q    = (const float*)d_in[0];
  const float* p    = (const float*)d_in[1];
  const float* t    = (const float*)d_in[2];
  const float* dt   = (const float*)d_in[3];
  const float* W0   = (const float*)d_in[4];
  const float* b0   = (const float*)d_in[5];
  const float* W1   = (const float*)d_in[6];
  const float* b1   = (const float*)d_in[7];
  const float* W2   = (const float*)d_in[8];
  const float* b2   = (const float*)d_in[9];
  const float* W3   = (const float*)d_in[10];
  const float* b3   = (const float*)d_in[11];
  const float* Wout = (const float*)d_in[12];
  const float* bout = (const float*)d_in[13];

  // ws layout (all bf16 activations)
  __hip_bfloat16* flatb = (__hip_bfloat16*)d_ws;                 // B*1024
  __hip_bfloat16* act1  = flatb + (size_t)BTOT * 1024;           // B*512
  __hip_bfloat16* act2  = act1 + (size_t)BTOT * 512;             // B*512
  __hip_bfloat16* pbf   = act2 + (size_t)BTOT * 512;             // B*32
  __hip_bfloat16* Wt0   = pbf + (size_t)BTOT * 32;
  __hip_bfloat16* Wt1   = Wt0 + 512 * 32;
  __hip_bfloat16* Wt2   = Wt1 + 512 * 512;
  __hip_bfloat16* Wt3   = Wt2 + 512 * 512;
  __hip_bfloat16* WtO   = Wt3 + 512 * 512;

  dim3 blk(256);
  convert_p_kernel<<<BTOT * 32 / 1024, blk, 0, stream>>>(p, pbf);
  transpose_w_kernel<<<dim3(1, 16),  blk, 0, stream>>>(W0,   Wt0, 32,  512);
  transpose_w_kernel<<<dim3(16, 16), blk, 0, stream>>>(W1,   Wt1, 512, 512);
  transpose_w_kernel<<<dim3(16, 16), blk, 0, stream>>>(W2,   Wt2, 512, 512);
  transpose_w_kernel<<<dim3(16, 16), blk, 0, stream>>>(W3,   Wt3, 512, 512);
  transpose_w_kernel<<<dim3(16, 32), blk, 0, stream>>>(Wout, WtO, 512, 1024);

  mlp_mfma_kernel<32, 0><<<dim3(128, 4), blk, 0, stream>>>(
      pbf, 32, 32, t, Wt0, W0 + 32 * 512, b0, act1, 512);
  mlp_mfma_kernel<32, 0><<<dim3(128, 4), blk, 0, stream>>>(
      act1, 512, 512, t, Wt1, W1 + 512 * 512, b1, act2, 512);
  mlp_mfma_kernel<32, 0><<<dim3(128, 4), blk, 0, stream>>>(
      act2, 512, 512, t, Wt2, W2 + 512 * 512, b2, act1, 512);
  mlp_mfma_kernel<32, 0><<<dim3(128, 4), blk, 0, stream>>>(
      act1, 512, 512, t, Wt3, W3 + 512 * 512, b3, act2, 512);
  mlp_mfma_kernel<32, 1><<<dim3(128, 8), blk, 0, stream>>>(
      act2, 512, 512, t, WtO, Wout + 512 * 1024, bout, flatb, 1024);

  float* out_q     = (float*)d_out;
  float* out_dlogp = out_q + (size_t)BTOT * 32;
  expm_chain_kernel<<<BTOT / 4, blk, 0, stream>>>(flatb, q, dt, out_q, out_dlogp);
}

// Round 8
// 157.340 us; speedup vs baseline: 1.0749x; 1.0749x over previous
//
#include <hip/hip_runtime.h>
#include <hip/hip_bf16.h>
#include <math.h>

#define BTOT 16384

typedef __attribute__((ext_vector_type(8))) short short8;
typedef __attribute__((ext_vector_type(4))) float f32x4;
typedef __attribute__((ext_vector_type(16))) float f32x16;

__device__ __forceinline__ float selu_f(float x) {
  const float scale = 1.0507009873554805f;
  const float alpha = 1.6732632423543772f;
  return scale * (x > 0.0f ? x : alpha * expm1f(x));
}

// ---------------- prep: p -> bf16 ----------------
__global__ __launch_bounds__(256) void convert_p_kernel(
    const float* __restrict__ p, __hip_bfloat16* __restrict__ out) {
  int i = (blockIdx.x * 256 + threadIdx.x) * 4;
  float4 v = *reinterpret_cast<const float4*>(p + i);
  out[i + 0] = __float2bfloat16(v.x);
  out[i + 1] = __float2bfloat16(v.y);
  out[i + 2] = __float2bfloat16(v.z);
  out[i + 3] = __float2bfloat16(v.w);
}

// ---------------- prep: W[K][N] f32 -> Wt[N][K] bf16 (t-row excluded) ---------
__global__ __launch_bounds__(256) void transpose_w_kernel(
    const float* __restrict__ W, __hip_bfloat16* __restrict__ Wt, int K, int N) {
  __shared__ float tile[32][33];
  const int kb = blockIdx.x * 32, nb = blockIdx.y * 32;
  const int tx = threadIdx.x & 31, ty = threadIdx.x >> 5;
  #pragma unroll
  for (int rr = 0; rr < 4; ++rr) {
    int kl = ty + rr * 8;
    tile[kl][tx] = W[(size_t)(kb + kl) * N + nb + tx];
  }
  __syncthreads();
  #pragma unroll
  for (int rr = 0; rr < 4; ++rr) {
    int nl = ty + rr * 8;
    Wt[(size_t)(nb + nl) * K + kb + tx] = __float2bfloat16(tile[tx][nl]);
  }
}

// ---------------- MFMA MLP layer ----------------
// MODE 0: selu + bf16 store (hidden).  MODE 1: clip(+-20) + bf16 store (final).
// BK=64 for K=512 layers (measured faster than BK=32: r6 163.8 vs r7 169.1).
template<int BK, int MODE>
__global__ __launch_bounds__(256) void mlp_mfma_kernel(
    const __hip_bfloat16* __restrict__ X, int ldx, int Kc,
    const float* __restrict__ tvec,
    const __hip_bfloat16* __restrict__ Wt,    // [N][Kc] bf16
    const float* __restrict__ Wlast,          // t-row, fp32 [N]
    const float* __restrict__ bias,           // fp32 [N]
    __hip_bfloat16* __restrict__ Yout, int ldy) {
  constexpr int NBLK = BK / 8;
  constexpr int AB = 128 * BK * 2;
  constexpr int IPW = AB / 1024 / 4;
  __shared__ char lds[4 * AB];
  const int tid = threadIdx.x;
  const int w = tid >> 6, lane = tid & 63;
  const int wr = w >> 1, wc = w & 1;
  const int rowbase = blockIdx.x * 128, colbase = blockIdx.y * 128;

  const __hip_bfloat16* srcA[IPW];
  const __hip_bfloat16* srcB[IPW];
  int ldsoff[IPW];
  #pragma unroll
  for (int i = 0; i < IPW; ++i) {
    int f = (w * IPW + i) * 64 + lane;
    int r = f / NBLK, slot = f % NBLK;
    int kb = slot ^ (r & (NBLK - 1));
    srcA[i] = X + (size_t)(rowbase + r) * ldx + kb * 8;
    srcB[i] = Wt + (size_t)(colbase + r) * Kc + kb * 8;
    ldsoff[i] = (w * IPW + i) * 1024;
  }

  f32x4 acc[4][4] = {};

  int aoff[4], amask[4], boff[4], bmask[4];
  #pragma unroll
  for (int i = 0; i < 4; ++i) {
    int ra = wr * 64 + i * 16 + (lane & 15);
    aoff[i] = ra * BK * 2;
    amask[i] = ra & (NBLK - 1);
    int cb = wc * 64 + i * 16 + (lane & 15);
    boff[i] = cb * BK * 2;
    bmask[i] = cb & (NBLK - 1);
  }
  const int kgrp = lane >> 4;

  auto stage_tile = [&](int buf, int t) {
    char* ab = lds + buf * 2 * AB;
    #pragma unroll
    for (int i = 0; i < IPW; ++i) {
      __builtin_amdgcn_global_load_lds(
          (const __attribute__((address_space(1))) void*)(srcA[i] + t * BK),
          (__attribute__((address_space(3))) void*)(ab + ldsoff[i]), 16, 0, 0);
      __builtin_amdgcn_global_load_lds(
          (const __attribute__((address_space(1))) void*)(srcB[i] + t * BK),
          (__attribute__((address_space(3))) void*)(ab + AB + ldsoff[i]), 16, 0, 0);
    }
  };

  auto compute_tile = [&](int buf) {
    const char* Abse = lds + buf * 2 * AB;
    const char* Bbse = Abse + AB;
    #pragma unroll
    for (int kh = 0; kh < BK / 32; ++kh) {
      short8 a[4], b[4];
      const int kb = kh * 4 + kgrp;
      #pragma unroll
      for (int i = 0; i < 4; ++i) {
        a[i] = *reinterpret_cast<const short8*>(Abse + aoff[i] + ((kb ^ amask[i]) * 16));
        b[i] = *reinterpret_cast<const short8*>(Bbse + boff[i] + ((kb ^ bmask[i]) * 16));
      }
      #pragma unroll
      for (int i = 0; i < 4; ++i)
        #pragma unroll
        for (int j = 0; j < 4; ++j)
          acc[i][j] = __builtin_amdgcn_mfma_f32_16x16x32_bf16(a[i], b[j], acc[i][j], 0, 0, 0);
    }
  };

  const int nt = Kc / BK;
  stage_tile(0, 0);
  asm volatile("s_waitcnt vmcnt(0)" ::: "memory");
  __syncthreads();
  int buf = 0;
  #pragma unroll 1
  for (int t = 0; t < nt - 1; ++t) {
    stage_tile(buf ^ 1, t + 1);
    compute_tile(buf);
    asm volatile("s_waitcnt vmcnt(0)" ::: "memory");
    __syncthreads();
    buf ^= 1;
  }
  compute_tile(buf);

  const int colloc = lane & 15;
  const int rowgrp = lane >> 4;
  float wl[4], bb[4];
  #pragma unroll
  for (int j = 0; j < 4; ++j) {
    int col = colbase + wc * 64 + j * 16 + colloc;
    wl[j] = Wlast[col];
    bb[j] = bias[col];
  }
  #pragma unroll
  for (int i = 0; i < 4; ++i) {
    #pragma unroll
    for (int e = 0; e < 4; ++e) {
      int row = rowbase + wr * 64 + i * 16 + rowgrp * 4 + e;
      float tv = tvec[row];
      #pragma unroll
      for (int j = 0; j < 4; ++j) {
        float v = acc[i][j][e] + tv * wl[j] + bb[j];
        if (MODE == 0) v = selu_f(v);
        else           v = fminf(fmaxf(v, -20.f), 20.f);
        int col = colbase + wc * 64 + j * 16 + colloc;
        Yout[(size_t)row * ldy + col] = __float2bfloat16(v);
      }
    }
  }
}

// ---------------- expm: transposed chain + MFMA matvec squaring ----------------
// One 32x32 matrix per wave, M = A^T. Chain Q(k+1) = M*Q(k) with Aop = M rows
// (= A columns, from LDS pair slab), Bop = d2b(Q D-layout). Register state
// accumulates E^T in D-layout => lane C holds ROW C of E. Squaring phase:
// v split hi/lo, Aop = v-broadcast, Bop = d2b(E^T) split hi/lo => one matvec =
// 16 bpermute + 16 perm + 6 MFMA, result (E.v)[C] identical in all D rows.
// Same (lane,e)->k bijection for A and B everywhere (HW-verified r4-r7).
#define WAITLDS asm volatile("s_waitcnt lgkmcnt(0)" ::: "memory")

__device__ __forceinline__ unsigned int bf16r(float x) {
  return (__float_as_uint(x) + 0x8000u) >> 16;
}

// D-layout f32 X -> B-operand frags (Bop[k][C] = X_mat[k][C]), k = 16h+8G+e
__device__ __forceinline__ void d2b(const float (&X)[16], int G, short8 (&bfr)[2]) {
  float oth[16];
  #pragma unroll
  for (int i = 0; i < 16; ++i) oth[i] = __shfl_xor(X[i], 32);
  #pragma unroll
  for (int h = 0; h < 2; ++h) {
    float r8[8];
    #pragma unroll
    for (int j2 = 0; j2 < 8; ++j2) {
      float g0 = (j2 < 4) ? X[8 * h + j2] : oth[8 * h + j2 - 4];
      float g1 = (j2 < 4) ? oth[8 * h + 4 + j2] : X[8 * h + j2];
      r8[j2] = G ? g1 : g0;
    }
    union { short8 s8; unsigned int u[4]; } bu;
    #pragma unroll
    for (int j = 0; j < 4; ++j)
      bu.u[j] = bf16r(r8[2 * j]) | (bf16r(r8[2 * j + 1]) << 16);
    bfr[h] = bu.s8;
  }
}

// Like d2b but emits hi (truncated bf16, exact) and lo (bf16 of residual) frags.
__device__ __forceinline__ void d2b_split(const float (&X)[16], int G,
                                          short8 (&bh)[2], short8 (&bl)[2]) {
  float oth[16];
  #pragma unroll
  for (int i = 0; i < 16; ++i) oth[i] = __shfl_xor(X[i], 32);
  #pragma unroll
  for (int h = 0; h < 2; ++h) {
    float r8[8];
    #pragma unroll
    for (int j2 = 0; j2 < 8; ++j2) {
      float g0 = (j2 < 4) ? X[8 * h + j2] : oth[8 * h + j2 - 4];
      float g1 = (j2 < 4) ? oth[8 * h + 4 + j2] : X[8 * h + j2];
      r8[j2] = G ? g1 : g0;
    }
    union { short8 s8; unsigned int u[4]; } uh, ul;
    #pragma unroll
    for (int j = 0; j < 4; ++j) {
      unsigned int b0 = __float_as_uint(r8[2 * j]) & 0xFFFF0000u;
      unsigned int b1 = __float_as_uint(r8[2 * j + 1]) & 0xFFFF0000u;
      float l0 = r8[2 * j] - __uint_as_float(b0);
      float l1 = r8[2 * j + 1] - __uint_as_float(b1);
      uh.u[j] = (b0 >> 16) | b1;
      ul.u[j] = bf16r(l0) | (bf16r(l1) << 16);
    }
    bh[h] = uh.s8;
    bl[h] = ul.s8;
  }
}

__global__ __launch_bounds__(256) void expm_tchain_kernel(
    const __hip_bfloat16* __restrict__ flat,  // [B,1024] bf16, pre-clipped
    const float* __restrict__ q,
    const float* __restrict__ dtp,
    float* __restrict__ out_q,
    float* __restrict__ out_dlogp) {
  __shared__ __align__(16) unsigned int SL[4][16][33];   // col-pair slab
  const int tid = threadIdx.x;
  const int w = tid >> 6, lane = tid & 63;
  const int C = lane & 31, G = lane >> 5;
  const int m = blockIdx.x * 4 + w;
  const float dt = dtp[0];

  // row-block load for LDS transpose: lane -> rows lane>>2 and 16+(lane>>2)
  const uint4* fm = reinterpret_cast<const uint4*>(flat + (size_t)m * 1024);
  uint4 v0 = fm[lane];
  uint4 v1 = fm[lane + 64];
  {
    const int r0 = lane >> 2, kpb = (lane & 3) * 4;
    SL[w][kpb + 0][r0] = v0.x; SL[w][kpb + 1][r0] = v0.y;
    SL[w][kpb + 2][r0] = v0.z; SL[w][kpb + 3][r0] = v0.w;
    SL[w][kpb + 0][r0 + 16] = v1.x; SL[w][kpb + 1][r0 + 16] = v1.y;
    SL[w][kpb + 2][r0 + 16] = v1.z; SL[w][kpb + 3][r0 + 16] = v1.w;
  }

  // afr load: row C, cols 8G..+8 and 16+8G..+8 == Bop frag of Q1 = M, verbatim
  union u4s8 { uint4 u4; short8 s8; unsigned int u[4]; };
  u4s8 t0, t1;
  {
    const char* base = reinterpret_cast<const char*>(flat) + (size_t)m * 2048 + C * 64 + G * 16;
    t0.u4 = *reinterpret_cast<const uint4*>(base);
    t1.u4 = *reinterpret_cast<const uint4*>(base + 32);
  }

  // inf-norm: row C abs-sum = own 16 elems + partner half
  float sa = 0.f;
  {
    unsigned int a0[4] = {t0.u[0], t0.u[1], t0.u[2], t0.u[3]};
    unsigned int a1[4] = {t1.u[0], t1.u[1], t1.u[2], t1.u[3]};
    #pragma unroll
    for (int i = 0; i < 4; ++i) {
      sa += fabsf(__uint_as_float(a0[i] << 16)) + fabsf(__uint_as_float(a0[i] & 0xFFFF0000u));
      sa += fabsf(__uint_as_float(a1[i] << 16)) + fabsf(__uint_as_float(a1[i] & 0xFFFF0000u));
    }
  }
  sa += __shfl_xor(sa, 32);
  float nrm = sa;
  #pragma unroll
  for (int off = 1; off < 32; off <<= 1) nrm = fmaxf(nrm, __shfl_xor(nrm, off));

  int s = 0;
  float anrm = dt * nrm;
  if (anrm > 1.5f) {
    s = (int)ceilf(log2f(anrm * (1.0f / 1.5f)));
    s = s < 1 ? 1 : (s > 6 ? 6 : s);
  }
  const float u = dt * exp2f(-(float)s);

  // E init: E = I + u*M (D-layout: lane (C,G) reg i holds M[rd][C] = A[C][rd]),
  // built from own + partner afr halves; also accumulate trace(A) on the fly.
  // reg block j: source t0 (j<2) else t1; own iff (j&1)==G; elem = 4G + e'.
  unsigned int pt0[4], pt1[4];
  #pragma unroll
  for (int d = 0; d < 4; ++d) {
    pt0[d] = (unsigned int)__shfl_xor((int)t0.u[d], 32);
    pt1[d] = (unsigned int)__shfl_xor((int)t1.u[d], 32);
  }
  float E[16], dIa[16];
  float tr = 0.f;
  #pragma unroll
  for (int j = 0; j < 4; ++j) {
    #pragma unroll
    for (int e2 = 0; e2 < 4; ++e2) {
      const int i = 4 * j + e2;
      const int rd = e2 + 8 * j + 4 * G;
      const bool own = ((j & 1) == G);
      // dword index = 2G + (e2>>1): static in both G arms (rule #20)
      unsigned int dwO, dwP;
      if ((e2 >> 1) == 0) {
        dwO = G ? ((j < 2) ? t0.u[2] : t1.u[2]) : ((j < 2) ? t0.u[0] : t1.u[0]);
        dwP = G ? ((j < 2) ? pt0[2] : pt1[2]) : ((j < 2) ? pt0[0] : pt1[0]);
      } else {
        dwO = G ? ((j < 2) ? t0.u[3] : t1.u[3]) : ((j < 2) ? t0.u[1] : t1.u[1]);
        dwP = G ? ((j < 2) ? pt0[3] : pt1[3]) : ((j < 2) ? pt0[1] : pt1[1]);
      }
      unsigned int dw = own ? dwO : dwP;
      unsigned int h16 = (e2 & 1) ? (dw >> 16) : (dw & 0xFFFFu);
      float mv = __uint_as_float(h16 << 16);
      float dI = (rd == C) ? 1.0f : 0.0f;
      dIa[i] = dI;
      E[i] = dI + u * mv;
      tr += dI * mv;
    }
  }
  #pragma unroll
  for (int off = 1; off < 64; off <<= 1) tr += __shfl_xor(tr, off);
  if (lane == 0) out_dlogp[m] = dt * tr;

  WAITLDS;

  // M A-operand frags: Mfr[h] elem e = M[C][16h+8G+e] = A[16h+8G+e][C]
  short8 Mfr[2];
  {
    const unsigned int selpat = (C & 1) ? 0x07060302u : 0x05040100u;
    #pragma unroll
    for (int h = 0; h < 2; ++h) {
      unsigned int rr[8];
      #pragma unroll
      for (int e = 0; e < 8; ++e) rr[e] = SL[w][C >> 1][16 * h + 8 * G + e];
      union { short8 s8; unsigned int u[4]; } mu;
      #pragma unroll
      for (int j = 0; j < 4; ++j)
        mu.u[j] = __builtin_amdgcn_perm(rr[2 * j + 1], rr[2 * j], selpat);
      Mfr[h] = mu.s8;
    }
  }

  // chain: Q(k+1) = M*Q(k); first product's Bop is the raw afr (t0,t1)
  float Qc[16];
  float ck = u * u * 0.5f;
  {
    f32x16 acc = {};
    acc = __builtin_amdgcn_mfma_f32_32x32x16_bf16(Mfr[0], t0.s8, acc, 0, 0, 0);
    acc = __builtin_amdgcn_mfma_f32_32x32x16_bf16(Mfr[1], t1.s8, acc, 0, 0, 0);
    #pragma unroll
    for (int i = 0; i < 16; ++i) { Qc[i] = acc[i]; E[i] += ck * Qc[i]; }
  }
  #pragma unroll
  for (int k = 3; k <= 8; ++k) {
    short8 bfr[2];
    d2b(Qc, G, bfr);
    f32x16 acc = {};
    acc = __builtin_amdgcn_mfma_f32_32x32x16_bf16(Mfr[0], bfr[0], acc, 0, 0, 0);
    acc = __builtin_amdgcn_mfma_f32_32x32x16_bf16(Mfr[1], bfr[1], acc, 0, 0, 0);
    ck *= u * (1.0f / (float)k);
    #pragma unroll
    for (int i = 0; i < 16; ++i) { Qc[i] = acc[i]; E[i] += ck * Qc[i]; }
  }

  // squaring phase: E^T in regs => Bop = d2b(E) gives Bop[k][C] = E[C][k];
  // Aop = v-broadcast => D[r][C] = sum_k v[k]*E[C][k] = (E.v)[C], all rows equal
  short8 beh[2], bel[2];
  d2b_split(E, G, beh, bel);

  float qv = q[(size_t)m * 32 + C];
  const int nv = 1 << s;
  #pragma unroll 1
  for (int it = 0; it < nv; ++it) {
    unsigned int hb = __float_as_uint(qv) & 0xFFFF0000u;
    float lof = qv - __uint_as_float(hb);
    unsigned int pw = (hb >> 16) | (bf16r(lof) << 16);   // lo16=vh, hi16=vl
    short8 vh[2], vl[2];
    #pragma unroll
    for (int h = 0; h < 2; ++h) {
      unsigned int g[8];
      #pragma unroll
      for (int e = 0; e < 8; ++e)
        g[e] = (unsigned int)__shfl((int)pw, 16 * h + 8 * G + e);
      union { short8 s8; unsigned int u[4]; } uh, ul;
      #pragma unroll
      for (int j = 0; j < 4; ++j) {
        uh.u[j] = __builtin_amdgcn_perm(g[2 * j + 1], g[2 * j], 0x05040100u);
        ul.u[j] = __builtin_amdgcn_perm(g[2 * j + 1], g[2 * j], 0x07060302u);
      }
      vh[h] = uh.s8;
      vl[h] = ul.s8;
    }
    f32x16 acc = {};
    acc = __builtin_amdgcn_mfma_f32_32x32x16_bf16(vh[0], beh[0], acc, 0, 0, 0);
    acc = __builtin_amdgcn_mfma_f32_32x32x16_bf16(vh[1], beh[1], acc, 0, 0, 0);
    acc = __builtin_amdgcn_mfma_f32_32x32x16_bf16(vl[0], beh[0], acc, 0, 0, 0);
    acc = __builtin_amdgcn_mfma_f32_32x32x16_bf16(vl[1], beh[1], acc, 0, 0, 0);
    acc = __builtin_amdgcn_mfma_f32_32x32x16_bf16(vh[0], bel[0], acc, 0, 0, 0);
    acc = __builtin_amdgcn_mfma_f32_32x32x16_bf16(vh[1], bel[1], acc, 0, 0, 0);
    qv = acc[0];
  }
  if (G == 0) out_q[(size_t)m * 32 + C] = qv;
}

extern "C" void kernel_launch(void* const* d_in, const int* in_sizes, int n_in,
                              void* d_out, int out_size, void* d_ws, size_t ws_size,
                              hipStream_t stream) {
  const float* q    = (const float*)d_in[0];
  const float* p    = (const float*)d_in[1];
  const float* t    = (const float*)d_in[2];
  const float* dt   = (const float*)d_in[3];
  const float* W0   = (const float*)d_in[4];
  const float* b0   = (const float*)d_in[5];
  const float* W1   = (const float*)d_in[6];
  const float* b1   = (const float*)d_in[7];
  const float* W2   = (const float*)d_in[8];
  const float* b2   = (const float*)d_in[9];
  const float* W3   = (const float*)d_in[10];
  const float* b3   = (const float*)d_in[11];
  const float* Wout = (const float*)d_in[12];
  const float* bout = (const float*)d_in[13];

  // ws layout (all bf16 activations)
  __hip_bfloat16* flatb = (__hip_bfloat16*)d_ws;                 // B*1024
  __hip_bfloat16* act1  = flatb + (size_t)BTOT * 1024;           // B*512
  __hip_bfloat16* act2  = act1 + (size_t)BTOT * 512;             // B*512
  __hip_bfloat16* pbf   = act2 + (size_t)BTOT * 512;             // B*32
  __hip_bfloat16* Wt0   = pbf + (size_t)BTOT * 32;
  __hip_bfloat16* Wt1   = Wt0 + 512 * 32;
  __hip_bfloat16* Wt2   = Wt1 + 512 * 512;
  __hip_bfloat16* Wt3   = Wt2 + 512 * 512;
  __hip_bfloat16* WtO   = Wt3 + 512 * 512;

  dim3 blk(256);
  convert_p_kernel<<<BTOT * 32 / 1024, blk, 0, stream>>>(p, pbf);
  transpose_w_kernel<<<dim3(1, 16),  blk, 0, stream>>>(W0,   Wt0, 32,  512);
  transpose_w_kernel<<<dim3(16, 16), blk, 0, stream>>>(W1,   Wt1, 512, 512);
  transpose_w_kernel<<<dim3(16, 16), blk, 0, stream>>>(W2,   Wt2, 512, 512);
  transpose_w_kernel<<<dim3(16, 16), blk, 0, stream>>>(W3,   Wt3, 512, 512);
  transpose_w_kernel<<<dim3(16, 32), blk, 0, stream>>>(Wout, WtO, 512, 1024);

  mlp_mfma_kernel<32, 0><<<dim3(128, 4), blk, 0, stream>>>(
      pbf, 32, 32, t, Wt0, W0 + 32 * 512, b0, act1, 512);
  mlp_mfma_kernel<64, 0><<<dim3(128, 4), blk, 0, stream>>>(
      act1, 512, 512, t, Wt1, W1 + 512 * 512, b1, act2, 512);
  mlp_mfma_kernel<64, 0><<<dim3(128, 4), blk, 0, stream>>>(
      act2, 512, 512, t, Wt2, W2 + 512 * 512, b2, act1, 512);
  mlp_mfma_kernel<64, 0><<<dim3(128, 4), blk, 0, stream>>>(
      act1, 512, 512, t, Wt3, W3 + 512 * 512, b3, act2, 512);
  mlp_mfma_kernel<64, 1><<<dim3(128, 8), blk, 0, stream>>>(
      act2, 512, 512, t, WtO, Wout + 512 * 1024, bout, flatb, 1024);

  float* out_q     = (float*)d_out;
  float* out_dlogp = out_q + (size_t)BTOT * 32;
  expm_tchain_kernel<<<BTOT / 4, blk, 0, stream>>>(flatb, q, dt, out_q, out_dlogp);
}